// Round 10
// baseline (503.297 us; speedup 1.0000x reference)
//
#include <hip/hip_runtime.h>

// ---------------------------------------------------------------------------
// LocallyConnectedNN: x[16384,256] -> conv3x3(1->16)+BN+ReLU -> conv2x2(16->32)
// +BN+ReLU -> conv1x1(32->64)+BN+ReLU -> FC(10816->10).
// Round 10: round-9's 5-launch fused-stats structure, but the atomicAdd
// accumulators are 64-way SPREAD (block adds into copy blockIdx&63) -- round-9
// counters showed the single-copy version serialized ~819K same-line atomics
// (k5 74->210us, VALUBusy 48->17%). Last-done block sums the 64 copies
// (200KB read, ~3us) and runs the BN finalize. k0 zeroes the region first.
// ws: fcB u32 [0,106496); ACC1/2/3+cnt [114688,186432); ST 229376+;
// a2 cache at byte 5MB (177MB, proven ws>=219MB in round 6).
// ---------------------------------------------------------------------------

#define ST_OFF 229376     // s1[16] t1[16] s2[32] t2[32] s3[64] t3[64]
#define ST1 ST_OFF
#define ST2 (ST_OFF + 32)
#define ST3 (ST_OFF + 96)
#define NSPREAD 64
#define ACC1 114688       // 64 copies x 256 floats: x-patch Cext
#define ACC2 131072       // 64 copies x 64 floats: conv2 S[32]|Q[32]
#define ACC3 135168       // 64 copies x 800 floats: C2 tiles[768]|S2[32]
#define CNT_OFF 186368    // 3 unsigned counters
#define ZB 114688         // zero range (floats): [114688, 186432)
#define ZN 71744
#define A2G_BYTE 5242880ull // a2 cache: [img][13 i][13 pix][32 ch] bf16, 177MB
#define FCB_N (13 * 8192) // fcB u32 at ws[0..106496)
#define A1S 24            // a1h LDS row stride (shorts)
#define A1B 384           // one a1 LDS buffer (16 rows x A1S)
#define A3P 1048          // a3buf image stride (shorts)

typedef __attribute__((ext_vector_type(8))) short bf16x8;
typedef __attribute__((ext_vector_type(4))) float f32x4;

__device__ __forceinline__ unsigned int f2bf(float f) {
  unsigned int u = __float_as_uint(f);
  return (u + 0x7fffu + ((u >> 16) & 1u)) >> 16;   // RTNE bf16 bits
}
// pack two floats to bf16x2 (round-half-up): 2 adds + 1 v_perm_b32
__device__ __forceinline__ unsigned int pkbf(float a, float b) {
  unsigned ua = __float_as_uint(a) + 0x8000u;
  unsigned ub = __float_as_uint(b) + 0x8000u;
  return __builtin_amdgcn_perm(ub, ua, 0x07060302u);
}
__device__ __forceinline__ short cvtbf(float a) {
  return (short)((__float_as_uint(a) + 0x8000u) >> 16);
}
// agent-scope atomic load: reads the device-coherent copy (no stale L2 line)
__device__ __forceinline__ float aload(const float* p) {
  return __hip_atomic_load(p, __ATOMIC_RELAXED, __HIP_MEMORY_SCOPE_AGENT);
}

// conv1 (3x3,1->16)+bn1(folded)+relu for output row r, swapped operands:
// A = w1*rs1 (m=ch), B = im2row (n=col j), C-init = rt1.
// D: col(lane&15)=j, row(4q+r)=ch -> ph[j][ch] write = 1 ds_write_b64.
__device__ __forceinline__ void conv1_mfma(
    const float* __restrict__ sxi,   // [256] one image (+finite pad after)
    short* ph_buf,                   // [2 bufs][16 j][A1S ch]
    int r, int b, int q, bf16x8 a1f, f32x4 c1i)
{
  bf16x8 bf = {0, 0, 0, 0, 0, 0, 0, 0};
  unsigned* bu = (unsigned*)&bf;
  if (q == 0) {
    bu[0] = pkbf(sxi[r * 16 + b],           sxi[r * 16 + b + 1]);
    bu[1] = pkbf(sxi[r * 16 + b + 2],       sxi[(r + 1) * 16 + b]);
    bu[2] = pkbf(sxi[(r + 1) * 16 + b + 1], sxi[(r + 1) * 16 + b + 2]);
    bu[3] = pkbf(sxi[(r + 2) * 16 + b],     sxi[(r + 2) * 16 + b + 1]);
  } else if (q == 1) {
    bu[0] = pkbf(sxi[(r + 2) * 16 + b + 2], 0.f);
  }
  f32x4 acc = c1i;
  acc = __builtin_amdgcn_mfma_f32_16x16x32_bf16(a1f, bf, acc, 0, 0, 0);
  float v0 = acc[0] > 0.f ? acc[0] : 0.f;
  float v1 = acc[1] > 0.f ? acc[1] : 0.f;
  float v2 = acc[2] > 0.f ? acc[2] : 0.f;
  float v3 = acc[3] > 0.f ? acc[3] : 0.f;
  uint2 pk;
  pk.x = pkbf(v0, v1);
  pk.y = pkbf(v2, v3);
  *(uint2*)(ph_buf + (r & 1) * A1B + b * A1S + 4 * q) = pk;
}

// conv1 A-frag: m=ch=b, k=tap 8q+j (zeros for tap>=9), scaled by rs1[b].
__device__ __forceinline__ bf16x8 conv1_afrag(const float* w1, float rs1b,
                                              int b, int q) {
  bf16x8 v;
#pragma unroll
  for (int j = 0; j < 8; ++j) {
    int tap = 8 * q + j;
    v[j] = (tap < 9) ? (short)f2bf(w1[b * 9 + tap] * rs1b) : (short)0;
  }
  return v;
}

// K0: pack fc_w into MFMA B-fragment order + zero accumulators/counters.
__global__ __launch_bounds__(256) void k0_fcB(
    const float* __restrict__ fcw, unsigned int* __restrict__ fcB)
{
  int F = blockIdx.x * 256 + threadIdx.x;
  if (F >= FCB_N) return;
  if (F < ZN) fcB[ZB + F] = 0u;     // zero spread ACC1/ACC2/ACC3 + counters
  int u = F & 3, q = (F >> 2) & 3, jj = (F >> 4) & 15;
  int mm = (F >> 8) & 31, i = F >> 13;
  int k0 = mm * 32 + q * 8 + u * 2;
  unsigned lo = 0, hi = 0;
  if (jj < 10) {
    int c0 = k0 >> 4, j0 = k0 & 15;
    if (j0 < 13) lo = f2bf(fcw[jj * 10816 + c0 * 169 + i * 13 + j0]);
    int c1 = (k0 + 1) >> 4, j1 = (k0 + 1) & 15;
    if (j1 < 13) hi = f2bf(fcw[jj * 10816 + c1 * 169 + i * 13 + j1]);
  }
  fcB[F] = lo | (hi << 16);
}

// K1: x patch-covariance via MFMA syrk (register-built frags; tap 9 = 1.0 so
// C[9][t]=S[t]) + spread atomics + last-block BN1 finalize.
__global__ __launch_bounds__(256) void k1_xsyrk(
    const float* __restrict__ x, const float* __restrict__ w1,
    const float* __restrict__ gamma, const float* __restrict__ beta,
    float* __restrict__ ws)
{
  __shared__ float sx[16 * 256];
  __shared__ bool islast;
  const int tid = threadIdx.x, w = tid >> 6, lane = tid & 63;
  const int b = lane & 15, q = lane >> 4;
  {
    const float4* xs = (const float4*)(x + (size_t)blockIdx.x * (16 * 256));
    float4* sd = (float4*)sx;
    for (int e = tid; e < 16 * 64; e += 256) sd[e] = xs[e];
  }
  __syncthreads();
  const int di = (b < 9) ? (b / 3) : 0;
  const int dj = (b < 9) ? (b - di * 3) : 0;
  const int h = q >> 1, jb = (q & 1) * 8;
  f32x4 acc = {0.f, 0.f, 0.f, 0.f};
#pragma unroll 1
  for (int t = 0; t < 4; ++t) {
    const float* sxi = sx + (w * 4 + t) * 256;
#pragma unroll 1
    for (int s = 0; s < 7; ++s) {
      bf16x8 af;
      unsigned* au = (unsigned*)&af;
      if (b < 9) {
        const float* srow = sxi + (2 * s + h + di) * 16 + dj;
#pragma unroll
        for (int cc = 0; cc < 4; ++cc) {
          float v0 = (jb + 2 * cc     < 14) ? srow[jb + 2 * cc]     : 0.f;
          float v1 = (jb + 2 * cc + 1 < 14) ? srow[jb + 2 * cc + 1] : 0.f;
          au[cc] = pkbf(v0, v1);
        }
      } else if (b == 9) {
#pragma unroll
        for (int cc = 0; cc < 4; ++cc) {
          unsigned lo = (jb + 2 * cc     < 14) ? 0x3F80u : 0u;
          unsigned hi = (jb + 2 * cc + 1 < 14) ? 0x3F800000u : 0u;
          au[cc] = lo | hi;
        }
      } else {
#pragma unroll
        for (int cc = 0; cc < 4; ++cc) au[cc] = 0u;
      }
      acc = __builtin_amdgcn_mfma_f32_16x16x32_bf16(af, af, acc, 0, 0, 0);
    }
  }
  __syncthreads();                 // done reading sx; reuse as reduce buffer
  float* redc = sx;
#pragma unroll
  for (int rr = 0; rr < 4; ++rr)
    redc[w * 256 + (4 * q + rr) * 16 + b] = acc[rr];
  __syncthreads();
  const int cp1 = (blockIdx.x & (NSPREAD - 1)) * 256;
  atomicAdd(&ws[ACC1 + cp1 + tid],
            redc[tid] + redc[256 + tid] + redc[512 + tid] + redc[768 + tid]);
  __threadfence();
  __syncthreads();
  if (tid == 0) {
    unsigned old = atomicAdd((unsigned*)(ws + CNT_OFF) + 0, 1u);
    islast = (old == 1023u);
  }
  __syncthreads();
  if (!islast) return;
  {
    float s = 0.f;
#pragma unroll 8
    for (int c = 0; c < NSPREAD; ++c) s += aload(ws + ACC1 + c * 256 + tid);
    redc[tid] = s;
  }
  __syncthreads();
  if (tid < 16) {
    float wr[9];
#pragma unroll
    for (int p = 0; p < 9; ++p) wr[p] = w1[tid * 9 + p];
    float msum = 0.f;
#pragma unroll
    for (int p = 0; p < 9; ++p) msum += wr[p] * redc[9 * 16 + p];
    float e2 = 0.f;
#pragma unroll
    for (int a = 0; a < 9; ++a)
#pragma unroll
      for (int bb = 0; bb < 9; ++bb)
        e2 += wr[a] * wr[bb] * redc[a * 16 + bb];
    const float inv_n = 1.0f / (16384.0f * 196.0f);
    float mean = msum * inv_n;
    float var  = e2 * inv_n - mean * mean;
    float sv   = gamma[tid] * rsqrtf(var + 1e-5f);
    ws[ST1 + tid]      = sv;
    ws[ST1 + 16 + tid] = beta[tid] - mean * sv;
  }
}

// K3: conv1(MFMA,folded) + conv2(swapped, raw) stats + spread atomics +
// last-block BN2 finalize.
__global__ __launch_bounds__(256) void k3_conv2_stats(
    const float* __restrict__ x, const float* __restrict__ w1,
    const float* __restrict__ w2, const float* __restrict__ gamma,
    const float* __restrict__ beta, float* __restrict__ ws)
{
  __shared__ float sx_s[16 * 256 + 16];
  __shared__ alignas(16) short a1h[4 * 2 * A1B];
  __shared__ float redf[256];
  __shared__ bool islast;
  const int tid = threadIdx.x, w = tid >> 6, lane = tid & 63;
  const int b = lane & 15, q = lane >> 4;
  {
    const float4* xs = (const float4*)(x + (size_t)blockIdx.x * (16 * 256));
    float4* sd = (float4*)sx_s;
    for (int e = tid; e < 16 * 64; e += 256) sd[e] = xs[e];
    if (tid < 16) sx_s[16 * 256 + tid] = 0.f;
  }
  bf16x8 a1f = conv1_afrag(w1, ws[ST1 + b], b, q);
  f32x4 c1i;
#pragma unroll
  for (int r = 0; r < 4; ++r) c1i[r] = ws[ST1 + 16 + 4 * q + r];
  bf16x8 b2h[4];   // A-side: [ks][nt], m=ch=b, raw
#pragma unroll
  for (int ks = 0; ks < 2; ++ks)
#pragma unroll
    for (int nt = 0; nt < 2; ++nt) {
      bf16x8 vh;
#pragma unroll
      for (int j = 0; j < 8; ++j) {
        int kk = 8 * (q & 1) + j, dj = q >> 1;
        vh[j] = (short)f2bf(w2[(nt * 16 + b) * 64 + kk * 4 + ks * 2 + dj]);
      }
      b2h[ks * 2 + nt] = vh;
    }
  const float vb = (b < 13) ? 1.f : 0.f;
  const int colAr = (b + (q >> 1) < 15) ? (b + (q >> 1)) : 15;
  const int offAl = colAr * A1S + 8 * (q & 1);
  __syncthreads();

  float s2r[2][4] = {{0.f,0.f,0.f,0.f},{0.f,0.f,0.f,0.f}};
  float q2r[2][4] = {{0.f,0.f,0.f,0.f},{0.f,0.f,0.f,0.f}};
  short* ph = a1h + w * (2 * A1B);
#pragma unroll 1
  for (int t = 0; t < 4; ++t) {
    const float* sxi = sx_s + (w * 4 + t) * 256;
    conv1_mfma(sxi, ph, 0, b, q, a1f, c1i);
    __builtin_amdgcn_wave_barrier();
#pragma unroll 1
    for (int i = 0; i < 13; ++i) {
      conv1_mfma(sxi, ph, i + 1, b, q, a1f, c1i);
      __builtin_amdgcn_wave_barrier();
      bf16x8 ah0 = *(const bf16x8*)(ph + (i & 1) * A1B + offAl);
      bf16x8 ah1 = *(const bf16x8*)(ph + ((i + 1) & 1) * A1B + offAl);
      f32x4 acc2[2] = {{0.f,0.f,0.f,0.f},{0.f,0.f,0.f,0.f}};
#pragma unroll
      for (int nt = 0; nt < 2; ++nt) {
        acc2[nt] = __builtin_amdgcn_mfma_f32_16x16x32_bf16(b2h[nt], ah0, acc2[nt], 0, 0, 0);
        acc2[nt] = __builtin_amdgcn_mfma_f32_16x16x32_bf16(b2h[2 + nt], ah1, acc2[nt], 0, 0, 0);
      }
#pragma unroll
      for (int nt = 0; nt < 2; ++nt)
#pragma unroll
        for (int r = 0; r < 4; ++r) {
          float ym = acc2[nt][r] * vb;
          s2r[nt][r] += ym;
          q2r[nt][r] = fmaf(ym, acc2[nt][r], q2r[nt][r]);
        }
      __builtin_amdgcn_wave_barrier();
    }
  }
  // reduce over the 16 pix-lanes (b); lane b==0 holds ch = nt*16+4q+r
#pragma unroll
  for (int nt = 0; nt < 2; ++nt)
#pragma unroll
    for (int r = 0; r < 4; ++r) {
      float sv = s2r[nt][r], qv = q2r[nt][r];
      sv += __shfl_xor(sv, 1); sv += __shfl_xor(sv, 2);
      sv += __shfl_xor(sv, 4); sv += __shfl_xor(sv, 8);
      qv += __shfl_xor(qv, 1); qv += __shfl_xor(qv, 2);
      qv += __shfl_xor(qv, 4); qv += __shfl_xor(qv, 8);
      if (b == 0) {
        redf[w * 64 + nt * 16 + 4 * q + r]      = sv;
        redf[w * 64 + 32 + nt * 16 + 4 * q + r] = qv;
      }
    }
  __syncthreads();
  const int cp2 = (blockIdx.x & (NSPREAD - 1)) * 64;
  if (tid < 64)
    atomicAdd(&ws[ACC2 + cp2 + tid],
              redf[tid] + redf[64 + tid] + redf[128 + tid] + redf[192 + tid]);
  __threadfence();
  __syncthreads();
  if (tid == 0) {
    unsigned old = atomicAdd((unsigned*)(ws + CNT_OFF) + 1, 1u);
    islast = (old == 1023u);
  }
  __syncthreads();
  if (!islast) return;
  if (tid < 64) {
    float s = 0.f;
#pragma unroll 8
    for (int c = 0; c < NSPREAD; ++c) s += aload(ws + ACC2 + c * 64 + tid);
    redf[tid] = s;
  }
  __syncthreads();
  if (tid < 32) {
    const float inv_n = 1.0f / (16384.0f * 169.0f);
    float mean = redf[tid] * inv_n;
    float var  = redf[32 + tid] * inv_n - mean * mean;
    float sv   = gamma[tid] * rsqrtf(var + 1e-5f);
    ws[ST2 + tid]      = sv;
    ws[ST2 + 32 + tid] = beta[tid] - mean * sv;
  }
}

// K5: conv1 + conv2 (both MFMA, BN-folded) -> a2 direct global stores + xt
// syrk for BN3 second moments + spread atomics + last-block BN3 finalize.
__global__ __launch_bounds__(256) void k5_a2(
    const float* __restrict__ x, const float* __restrict__ w1,
    const float* __restrict__ w2, const float* __restrict__ w3,
    const float* __restrict__ gamma, const float* __restrict__ beta,
    float* __restrict__ ws, short* __restrict__ a2g)
{
  __shared__ float sx_s[16 * 256 + 16];          // reused as redc at the end
  __shared__ alignas(16) short a1h[4 * 2 * A1B];
  __shared__ alignas(16) short xt4[4 * 32 * 40]; // [w][ch32][pos32+pad8]
  __shared__ float s2red[4 * 32];
  __shared__ bool islast;
  const int tid = threadIdx.x, w = tid >> 6, lane = tid & 63;
  const int b = lane & 15, q = lane >> 4;
  {
    const float4* xs = (const float4*)(x + (size_t)blockIdx.x * (16 * 256));
    float4* sd = (float4*)sx_s;
    for (int e = tid; e < 16 * 64; e += 256) sd[e] = xs[e];
    if (tid < 16) sx_s[16 * 256 + tid] = 0.f;
  }
  bf16x8 a1f = conv1_afrag(w1, ws[ST1 + b], b, q);
  f32x4 c1i;
#pragma unroll
  for (int r = 0; r < 4; ++r) c1i[r] = ws[ST1 + 16 + 4 * q + r];
  bf16x8 b2h[4];   // A-side: [ks][nt], m=ch=b, scaled by s2[nt*16+b]
#pragma unroll
  for (int ks = 0; ks < 2; ++ks)
#pragma unroll
    for (int nt = 0; nt < 2; ++nt) {
      float rs2b = ws[ST2 + nt * 16 + b];
      bf16x8 vh;
#pragma unroll
      for (int j = 0; j < 8; ++j) {
        int kk = 8 * (q & 1) + j, dj = q >> 1;
        vh[j] = (short)f2bf(w2[(nt * 16 + b) * 64 + kk * 4 + ks * 2 + dj] * rs2b);
      }
      b2h[ks * 2 + nt] = vh;
    }
  f32x4 c2i[2];
#pragma unroll
  for (int nt = 0; nt < 2; ++nt)
#pragma unroll
    for (int r = 0; r < 4; ++r)
      c2i[nt][r] = (b < 13) ? ws[ST2 + 32 + nt * 16 + 4 * q + r] : -1e30f;
  const int colAr = (b + (q >> 1) < 15) ? (b + (q >> 1)) : 15;
  const int offAl = colAr * A1S + 8 * (q & 1);
  short* xt = xt4 + w * 1280;
  __syncthreads();

  f32x4 accT0 = {0.f,0.f,0.f,0.f}, accT1 = {0.f,0.f,0.f,0.f},
        accT2 = {0.f,0.f,0.f,0.f};
  float s2aR[2][4] = {{0.f,0.f,0.f,0.f},{0.f,0.f,0.f,0.f}};
  short* ph = a1h + w * (2 * A1B);
#pragma unroll 1
  for (int t = 0; t < 4; ++t) {
    const int img = blockIdx.x * 16 + w * 4 + t;
    const float* sxi = sx_s + (w * 4 + t) * 256;
    conv1_mfma(sxi, ph, 0, b, q, a1f, c1i);
    __builtin_amdgcn_wave_barrier();
#pragma unroll 1
    for (int i = 0; i < 13; ++i) {
      conv1_mfma(sxi, ph, i + 1, b, q, a1f, c1i);
      __builtin_amdgcn_wave_barrier();
      bf16x8 ah0 = *(const bf16x8*)(ph + (i & 1) * A1B + offAl);
      bf16x8 ah1 = *(const bf16x8*)(ph + ((i + 1) & 1) * A1B + offAl);
#pragma unroll
      for (int nt = 0; nt < 2; ++nt) {
        f32x4 acc2 = c2i[nt];
        acc2 = __builtin_amdgcn_mfma_f32_16x16x32_bf16(b2h[nt], ah0, acc2, 0, 0, 0);
        acc2 = __builtin_amdgcn_mfma_f32_16x16x32_bf16(b2h[2 + nt], ah1, acc2, 0, 0, 0);
        float vm[4];
#pragma unroll
        for (int r = 0; r < 4; ++r) {
          vm[r] = acc2[r] > 0.f ? acc2[r] : 0.f;
          s2aR[nt][r] += vm[r];
          xt[(nt * 16 + 4 * q + r) * 40 + (i & 1) * 16 + b] = cvtbf(vm[r]);
        }
        if (b < 13) {
          uint2 pk;
          pk.x = pkbf(vm[0], vm[1]);
          pk.y = pkbf(vm[2], vm[3]);
          *(uint2*)(a2g + (size_t)img * 5408 + (size_t)(i * 13 + b) * 32 +
                    nt * 16 + 4 * q) = pk;
        }
      }
      __builtin_amdgcn_wave_barrier();
      if (i & 1) {   // syrk over position pair (i-1, i)
        bf16x8 xf0 = *(const bf16x8*)(xt + b * 40 + 8 * q);
        bf16x8 xf1 = *(const bf16x8*)(xt + (16 + b) * 40 + 8 * q);
        accT0 = __builtin_amdgcn_mfma_f32_16x16x32_bf16(xf0, xf0, accT0, 0, 0, 0);
        accT1 = __builtin_amdgcn_mfma_f32_16x16x32_bf16(xf0, xf1, accT1, 0, 0, 0);
        accT2 = __builtin_amdgcn_mfma_f32_16x16x32_bf16(xf1, xf1, accT2, 0, 0, 0);
      }
      __builtin_amdgcn_wave_barrier();
    }
    // leftover row 12 (parity 0): zero parity-1 halves, final syrk
    {
      uint2 z; z.x = 0u; z.y = 0u;
      *(uint2*)(xt + b * 40 + 16 + 4 * q) = z;
      *(uint2*)(xt + (16 + b) * 40 + 16 + 4 * q) = z;
      __builtin_amdgcn_wave_barrier();
      bf16x8 xf0 = *(const bf16x8*)(xt + b * 40 + 8 * q);
      bf16x8 xf1 = *(const bf16x8*)(xt + (16 + b) * 40 + 8 * q);
      accT0 = __builtin_amdgcn_mfma_f32_16x16x32_bf16(xf0, xf0, accT0, 0, 0, 0);
      accT1 = __builtin_amdgcn_mfma_f32_16x16x32_bf16(xf0, xf1, accT1, 0, 0, 0);
      accT2 = __builtin_amdgcn_mfma_f32_16x16x32_bf16(xf1, xf1, accT2, 0, 0, 0);
      __builtin_amdgcn_wave_barrier();
    }
  }
  // S2: reduce over pix-lanes b; lane b==0 holds ch = nt*16+4q+r
#pragma unroll
  for (int nt = 0; nt < 2; ++nt)
#pragma unroll
    for (int r = 0; r < 4; ++r) {
      float sv = s2aR[nt][r];
      sv += __shfl_xor(sv, 1); sv += __shfl_xor(sv, 2);
      sv += __shfl_xor(sv, 4); sv += __shfl_xor(sv, 8);
      if (b == 0) s2red[w * 32 + nt * 16 + 4 * q + r] = sv;
    }
  float* redc = sx_s;   // wave w writes only into its own sx quarter
#pragma unroll
  for (int rr = 0; rr < 4; ++rr) {
    int m = 4 * q + rr;
    redc[w * 1024 + 0   + m * 16 + b] = accT0[rr];
    redc[w * 1024 + 256 + m * 16 + b] = accT1[rr];
    redc[w * 1024 + 512 + m * 16 + b] = accT2[rr];
  }
  __syncthreads();
  const int cp3 = (blockIdx.x & (NSPREAD - 1)) * 800;
  for (int e = tid; e < 768; e += 256)
    atomicAdd(&ws[ACC3 + cp3 + e],
              redc[e] + redc[1024 + e] + redc[2048 + e] + redc[3072 + e]);
  if (tid < 32)
    atomicAdd(&ws[ACC3 + cp3 + 768 + tid],
              s2red[tid] + s2red[32 + tid] + s2red[64 + tid] + s2red[96 + tid]);
  __threadfence();
  __syncthreads();
  if (tid == 0) {
    unsigned old = atomicAdd((unsigned*)(ws + CNT_OFF) + 2, 1u);
    islast = (old == 1023u);
  }
  __syncthreads();
  if (!islast) return;
  // BN3 finalize: mean = w3^T S2 /N, E[y3^2] = w3^T C2 w3 /N.
  for (int e = tid; e < 800; e += 256) {
    float s = 0.f;
#pragma unroll 8
    for (int c = 0; c < NSPREAD; ++c) s += aload(ws + ACC3 + c * 800 + e);
    redc[e] = s;
  }
  __syncthreads();
  {
    const int c3 = tid & 63, seg = tid >> 6;
    float wr[32];
#pragma unroll
    for (int k = 0; k < 32; ++k) wr[k] = w3[c3 * 32 + k];
    float e2p = 0.f;
    for (int a = seg * 4; a < seg * 4 + 4; ++a)
#pragma unroll
      for (int bb = 0; bb < 16; ++bb) {
        e2p += wr[a] * wr[bb] * redc[a * 16 + bb];                  // T00
        e2p += wr[16 + a] * wr[16 + bb] * redc[512 + a * 16 + bb];  // T11
        e2p += 2.f * wr[a] * wr[16 + bb] * redc[256 + a * 16 + bb]; // T01
      }
    float msum = 0.f;
    if (seg == 0) {
#pragma unroll
      for (int k = 0; k < 32; ++k) msum += wr[k] * redc[768 + k];
    }
    __syncthreads();
    redc[1024 + seg * 64 + c3] = e2p;
    if (seg == 0) redc[1280 + c3] = msum;
  }
  __syncthreads();
  if (tid < 64) {
    const float inv_n = 1.0f / (16384.0f * 169.0f);
    float e2 = redc[1024 + tid] + redc[1088 + tid] +
               redc[1152 + tid] + redc[1216 + tid];
    float mean = redc[1280 + tid] * inv_n;
    float var  = e2 * inv_n - mean * mean;
    float sv   = gamma[tid] * rsqrtf(var + 1e-5f);
    ws[ST3 + tid]      = sv;
    ws[ST3 + 64 + tid] = beta[tid] - mean * sv;
  }
}

// K7: read packed a2 -> conv3(bn3-folded)+relu (MFMA) -> FC (MFMA).
__global__ __launch_bounds__(256) void k7_fc(
    const short* __restrict__ a2g, const float* __restrict__ w3,
    const float* __restrict__ fcb, const float* __restrict__ ws,
    float* __restrict__ out)
{
  __shared__ alignas(16) short a3buf[16 * A3P];
  const int tid = threadIdx.x, w = tid >> 6, lane = tid & 63;
  const int b = lane & 15, q = lane >> 4;
  bf16x8 b3h[4];     // B-side: n=ch=nt*16+b, scaled by s3
  f32x4 c3i[4];
#pragma unroll
  for (int nt = 0; nt < 4; ++nt) {
    float s3 = ws[ST3 + nt * 16 + b];
    float t3 = ws[ST3 + 64 + nt * 16 + b];
    bf16x8 vh;
#pragma unroll
    for (int j = 0; j < 8; ++j)
      vh[j] = (short)f2bf(w3[(nt * 16 + b) * 32 + 8 * q + j] * s3);
    b3h[nt] = vh;
    c3i[nt][0] = t3;                          // pix = 4q valid always
#pragma unroll
    for (int r = 1; r < 4; ++r)
      c3i[nt][r] = (q < 3) ? t3 : -1e30f;     // pix 4q+r invalid at q==3
  }
  const bf16x8* fcB = (const bf16x8*)ws;
  f32x4 accF = {0.f, 0.f, 0.f, 0.f};
  const int pixc = (b < 12) ? b : 12;   // clamp pad rows (relu(-1e30)=0 masks)
  size_t ib[4];
#pragma unroll
  for (int t = 0; t < 4; ++t)
    ib[t] = (size_t)(blockIdx.x * 16 + w * 4 + t) * 5408;
  bf16x8 a2pre[4];
#pragma unroll
  for (int t = 0; t < 4; ++t)
    a2pre[t] = *(const bf16x8*)(a2g + ib[t] + pixc * 32 + 8 * q);

#pragma unroll 1
  for (int i = 0; i < 13; ++i) {
    bf16x8 a2cur[4];
#pragma unroll
    for (int t = 0; t < 4; ++t) a2cur[t] = a2pre[t];
    if (i < 12) {
#pragma unroll
      for (int t = 0; t < 4; ++t)
        a2pre[t] = *(const bf16x8*)(a2g + ib[t] +
                                    (size_t)((i + 1) * 13 + pixc) * 32 + 8 * q);
    }
#pragma unroll
    for (int t = 0; t < 4; ++t) {
      const int g = w * 4 + t;
#pragma unroll
      for (int nt = 0; nt < 4; ++nt) {
        f32x4 acc3 = c3i[nt];
        acc3 = __builtin_amdgcn_mfma_f32_16x16x32_bf16(a2cur[t], b3h[nt], acc3, 0, 0, 0);
        float v0 = acc3[0] > 0.f ? acc3[0] : 0.f;
        float v1 = acc3[1] > 0.f ? acc3[1] : 0.f;
        float v2 = acc3[2] > 0.f ? acc3[2] : 0.f;
        float v3 = acc3[3] > 0.f ? acc3[3] : 0.f;
        uint2 pk2;
        pk2.x = pkbf(v0, v1);
        pk2.y = pkbf(v2, v3);
        *(uint2*)(a3buf + g * A3P + (nt * 16 + b) * 16 + 4 * q) = pk2;
      }
    }
    __syncthreads();          // a3buf complete for all 16 images
#pragma unroll
    for (int mm = 0; mm < 8; ++mm) {
      bf16x8 af = *(const bf16x8*)(a3buf + b * A3P + w * 256 + mm * 32 + 8 * q);
      bf16x8 bw = fcB[((i * 32 + w * 8 + mm) * 16 + b) * 4 + q];
      accF = __builtin_amdgcn_mfma_f32_16x16x32_bf16(af, bw, accF, 0, 0, 0);
    }
    __syncthreads();          // before next row overwrites a3buf
  }

  float* redf7 = (float*)a3buf;
#pragma unroll
  for (int r = 0; r < 4; ++r)
    redf7[w * 256 + (4 * q + r) * 16 + b] = accF[r];
  __syncthreads();
  if (tid < 160) {
    int img = tid / 10, jj = tid - img * 10;
    float s = redf7[img * 16 + jj] + redf7[256 + img * 16 + jj] +
              redf7[512 + img * 16 + jj] + redf7[768 + img * 16 + jj];
    out[(blockIdx.x * 16 + img) * 10 + jj] = s + fcb[jj];
  }
}

extern "C" void kernel_launch(void* const* d_in, const int* in_sizes, int n_in,
                              void* d_out, int out_size, void* d_ws, size_t ws_size,
                              hipStream_t stream) {
  (void)in_sizes; (void)n_in; (void)out_size; (void)ws_size;
  const float* x   = (const float*)d_in[0];
  const float* w1  = (const float*)d_in[1];
  const float* w2  = (const float*)d_in[2];
  const float* w3  = (const float*)d_in[3];
  const float* g1  = (const float*)d_in[4];
  const float* b1  = (const float*)d_in[5];
  const float* g2  = (const float*)d_in[6];
  const float* b2  = (const float*)d_in[7];
  const float* g3  = (const float*)d_in[8];
  const float* b3  = (const float*)d_in[9];
  const float* fcw = (const float*)d_in[10];
  const float* fcb = (const float*)d_in[11];
  float* out = (float*)d_out;
  float* ws  = (float*)d_ws;
  short* a2g = (short*)((char*)d_ws + A2G_BYTE);

  k0_fcB<<<FCB_N / 256, 256, 0, stream>>>(fcw, (unsigned int*)ws);
  k1_xsyrk<<<1024, 256, 0, stream>>>(x, w1, g1, b1, ws);
  k3_conv2_stats<<<1024, 256, 0, stream>>>(x, w1, w2, g2, b2, ws);
  k5_a2<<<1024, 256, 0, stream>>>(x, w1, w2, w3, g3, b3, ws, a2g);
  k7_fc<<<1024, 256, 0, stream>>>(a2g, w3, fcb, ws, out);
}

// Round 11
// 294.173 us; speedup vs baseline: 1.7109x; 1.7109x over previous
//
#include <hip/hip_runtime.h>

// ---------------------------------------------------------------------------
// LocallyConnectedNN: x[16384,256] -> conv3x3(1->16)+BN+ReLU -> conv2x2(16->32)
// +BN+ReLU -> conv1x1(32->64)+BN+ReLU -> FC(10816->10).
// Round 11: REVERT to round-8's proven hot kernels (279us; rounds 9/10 showed
// fused stats via atomics either serialize on ~50 cache lines (r9: +136us) or
// blow the hot kernel's VGPR budget via the cold finalize path (r10: VGPR
// 52->140, occ 32->11%)). Overhead shaved instead by: k0 merged into k1's
// launch (grid branch); reduce+finalize pairs merged into single tiny kernels
// via 1-atomic-per-block counters (register bloat isolated in tiny kernels).
// 10 launches -> 7. k3/k5/k7 are byte-identical to round 8.
// ws floats: fcB [0,106496); ST 229376..; C1R 231424; C2R 231680; CNT 232480;
// parts(k1/k5) 262144..1081344; k3 partials 1081344..1146880; a2g byte 5MB.
// ---------------------------------------------------------------------------

#define ST_OFF 229376     // s1[16] t1[16] s2[32] t2[32] s3[64] t3[64]
#define ST1 ST_OFF
#define ST2 (ST_OFF + 32)
#define ST3 (ST_OFF + 96)
#define C1R_OFF 231424    // reduced x-patch Cext [256]
#define C2R_OFF 231680    // reduced C2 tiles[768] | S2[32]
#define CNT_OFF 232480    // 2 unsigned counters (zeroed by k01 each call)
#define PARTS_OFF 262144  // k1 [1024][256] / k5 [1024][800] block partials
#define P2P_OFF 1081344   // k3 [1024][64] block partials
#define A2G_BYTE 5242880ull // a2 cache: [img][13 i][13 pix][32 ch] bf16, 177MB
#define FCB_N (13 * 8192) // fcB u32 at ws[0..106496)
#define A1S 24            // a1h LDS row stride (shorts)
#define A1B 384           // one a1 LDS buffer (16 rows x A1S)
#define A3P 1048          // a3buf image stride (shorts)

typedef __attribute__((ext_vector_type(8))) short bf16x8;
typedef __attribute__((ext_vector_type(4))) float f32x4;

__device__ __forceinline__ unsigned int f2bf(float f) {
  unsigned int u = __float_as_uint(f);
  return (u + 0x7fffu + ((u >> 16) & 1u)) >> 16;   // RTNE bf16 bits
}
// pack two floats to bf16x2 (round-half-up): 2 adds + 1 v_perm_b32
__device__ __forceinline__ unsigned int pkbf(float a, float b) {
  unsigned ua = __float_as_uint(a) + 0x8000u;
  unsigned ub = __float_as_uint(b) + 0x8000u;
  return __builtin_amdgcn_perm(ub, ua, 0x07060302u);
}
__device__ __forceinline__ short cvtbf(float a) {
  return (short)((__float_as_uint(a) + 0x8000u) >> 16);
}
// agent-scope atomic load: bypasses stale per-XCD L2 lines
__device__ __forceinline__ float aload(const float* p) {
  return __hip_atomic_load(p, __ATOMIC_RELAXED, __HIP_MEMORY_SCOPE_AGENT);
}

// conv1 (3x3,1->16)+bn1(folded)+relu for output row r, swapped operands:
// A = w1*rs1 (m=ch), B = im2row (n=col j), C-init = rt1.
// D: col(lane&15)=j, row(4q+r)=ch -> ph[j][ch] write = 1 ds_write_b64.
__device__ __forceinline__ void conv1_mfma(
    const float* __restrict__ sxi,   // [256] one image (+finite pad after)
    short* ph_buf,                   // [2 bufs][16 j][A1S ch]
    int r, int b, int q, bf16x8 a1f, f32x4 c1i)
{
  bf16x8 bf = {0, 0, 0, 0, 0, 0, 0, 0};
  unsigned* bu = (unsigned*)&bf;
  if (q == 0) {
    bu[0] = pkbf(sxi[r * 16 + b],           sxi[r * 16 + b + 1]);
    bu[1] = pkbf(sxi[r * 16 + b + 2],       sxi[(r + 1) * 16 + b]);
    bu[2] = pkbf(sxi[(r + 1) * 16 + b + 1], sxi[(r + 1) * 16 + b + 2]);
    bu[3] = pkbf(sxi[(r + 2) * 16 + b],     sxi[(r + 2) * 16 + b + 1]);
  } else if (q == 1) {
    bu[0] = pkbf(sxi[(r + 2) * 16 + b + 2], 0.f);
  }
  f32x4 acc = c1i;
  acc = __builtin_amdgcn_mfma_f32_16x16x32_bf16(a1f, bf, acc, 0, 0, 0);
  float v0 = acc[0] > 0.f ? acc[0] : 0.f;
  float v1 = acc[1] > 0.f ? acc[1] : 0.f;
  float v2 = acc[2] > 0.f ? acc[2] : 0.f;
  float v3 = acc[3] > 0.f ? acc[3] : 0.f;
  uint2 pk;
  pk.x = pkbf(v0, v1);
  pk.y = pkbf(v2, v3);
  *(uint2*)(ph_buf + (r & 1) * A1B + b * A1S + 4 * q) = pk;
}

// conv1 A-frag: m=ch=b, k=tap 8q+j (zeros for tap>=9), scaled by rs1[b].
__device__ __forceinline__ bf16x8 conv1_afrag(const float* w1, float rs1b,
                                              int b, int q) {
  bf16x8 v;
#pragma unroll
  for (int j = 0; j < 8; ++j) {
    int tap = 8 * q + j;
    v[j] = (tap < 9) ? (short)f2bf(w1[b * 9 + tap] * rs1b) : (short)0;
  }
  return v;
}

// K01: blocks [0,1024) = x patch-covariance MFMA syrk -> parts;
//      blocks [1024,1440) = fcB pack (+ zero the 2 counters).
__global__ __launch_bounds__(256) void k01(
    const float* __restrict__ x, const float* __restrict__ fcw,
    float* __restrict__ parts, unsigned int* __restrict__ fcB)
{
  __shared__ float sx[16 * 256];
  const int tid = threadIdx.x;
  if (blockIdx.x >= 1024) {
    int F = (blockIdx.x - 1024) * 256 + tid;
    if (F < 8) fcB[CNT_OFF + F] = 0u;
    int u = F & 3, q = (F >> 2) & 3, jj = (F >> 4) & 15;
    int mm = (F >> 8) & 31, i = F >> 13;
    int k0 = mm * 32 + q * 8 + u * 2;
    unsigned lo = 0, hi = 0;
    if (jj < 10) {
      int c0 = k0 >> 4, j0 = k0 & 15;
      if (j0 < 13) lo = f2bf(fcw[jj * 10816 + c0 * 169 + i * 13 + j0]);
      int c1 = (k0 + 1) >> 4, j1 = (k0 + 1) & 15;
      if (j1 < 13) hi = f2bf(fcw[jj * 10816 + c1 * 169 + i * 13 + j1]);
    }
    fcB[F] = lo | (hi << 16);
    return;
  }
  const int w = tid >> 6, lane = tid & 63;
  const int b = lane & 15, q = lane >> 4;
  {
    const float4* xs = (const float4*)(x + (size_t)blockIdx.x * (16 * 256));
    float4* sd = (float4*)sx;
    for (int e = tid; e < 16 * 64; e += 256) sd[e] = xs[e];
  }
  __syncthreads();
  const int di = (b < 9) ? (b / 3) : 0;
  const int dj = (b < 9) ? (b - di * 3) : 0;
  const int h = q >> 1, jb = (q & 1) * 8;
  f32x4 acc = {0.f, 0.f, 0.f, 0.f};
#pragma unroll 1
  for (int t = 0; t < 4; ++t) {
    const float* sxi = sx + (w * 4 + t) * 256;
#pragma unroll 1
    for (int s = 0; s < 7; ++s) {
      bf16x8 af;
      unsigned* au = (unsigned*)&af;
      if (b < 9) {
        const float* srow = sxi + (2 * s + h + di) * 16 + dj;
#pragma unroll
        for (int cc = 0; cc < 4; ++cc) {
          float v0 = (jb + 2 * cc     < 14) ? srow[jb + 2 * cc]     : 0.f;
          float v1 = (jb + 2 * cc + 1 < 14) ? srow[jb + 2 * cc + 1] : 0.f;
          au[cc] = pkbf(v0, v1);
        }
      } else if (b == 9) {
#pragma unroll
        for (int cc = 0; cc < 4; ++cc) {
          unsigned lo = (jb + 2 * cc     < 14) ? 0x3F80u : 0u;
          unsigned hi = (jb + 2 * cc + 1 < 14) ? 0x3F800000u : 0u;
          au[cc] = lo | hi;
        }
      } else {
#pragma unroll
        for (int cc = 0; cc < 4; ++cc) au[cc] = 0u;
      }
      acc = __builtin_amdgcn_mfma_f32_16x16x32_bf16(af, af, acc, 0, 0, 0);
    }
  }
  __syncthreads();                 // done reading sx; reuse as reduce buffer
  float* redc = sx;
#pragma unroll
  for (int rr = 0; rr < 4; ++rr)
    redc[w * 256 + (4 * q + rr) * 16 + b] = acc[rr];
  __syncthreads();
  parts[blockIdx.x * 256 + tid] =
      redc[tid] + redc[256 + tid] + redc[512 + tid] + redc[768 + tid];
}

// K_stats1m: 256 blocks reduce parts [1024][256] -> C1R; last block runs the
// BN1 finalize (mean = w^T S /N, E[y^2] = w^T C w /N).
__global__ __launch_bounds__(256) void k_stats1m(
    const float* __restrict__ parts, const float* __restrict__ w1,
    const float* __restrict__ gamma, const float* __restrict__ beta,
    float* __restrict__ ws)
{
  __shared__ float rs[4];
  __shared__ float rc[256];
  __shared__ bool islast;
  const int e = blockIdx.x, tid = threadIdx.x;
  const int w = tid >> 6, lane = tid & 63;
  float s = 0.f;
#pragma unroll 4
  for (int i = tid; i < 1024; i += 256) s += parts[i * 256 + e];
#pragma unroll
  for (int d = 1; d < 64; d <<= 1) s += __shfl_xor(s, d);
  if (lane == 0) rs[w] = s;
  __syncthreads();
  if (tid == 0) {
    ws[C1R_OFF + e] = rs[0] + rs[1] + rs[2] + rs[3];
    __threadfence();
    unsigned old = atomicAdd((unsigned*)ws + CNT_OFF + 0, 1u);
    islast = (old == 255u);
  }
  __syncthreads();
  if (!islast) return;
  rc[tid] = aload(ws + C1R_OFF + tid);
  __syncthreads();
  if (tid < 16) {
    float wr[9];
#pragma unroll
    for (int p = 0; p < 9; ++p) wr[p] = w1[tid * 9 + p];
    float msum = 0.f;
#pragma unroll
    for (int p = 0; p < 9; ++p) msum += wr[p] * rc[9 * 16 + p];
    float e2 = 0.f;
#pragma unroll
    for (int a = 0; a < 9; ++a)
#pragma unroll
      for (int bb = 0; bb < 9; ++bb)
        e2 += wr[a] * wr[bb] * rc[a * 16 + bb];
    const float inv_n = 1.0f / (16384.0f * 196.0f);
    float mean = msum * inv_n;
    float var  = e2 * inv_n - mean * mean;
    float sv   = gamma[tid] * rsqrtf(var + 1e-5f);
    ws[ST1 + tid]      = sv;
    ws[ST1 + 16 + tid] = beta[tid] - mean * sv;
  }
}

// K3: conv1(MFMA,folded) + conv2(swapped, raw) stats -> block partials.
__global__ __launch_bounds__(256) void k3_conv2_stats(
    const float* __restrict__ x, const float* __restrict__ w1,
    const float* __restrict__ w2, float* __restrict__ ws)
{
  __shared__ float sx_s[16 * 256 + 16];
  __shared__ alignas(16) short a1h[4 * 2 * A1B];
  __shared__ float redf[256];
  const int tid = threadIdx.x, w = tid >> 6, lane = tid & 63;
  const int b = lane & 15, q = lane >> 4;
  {
    const float4* xs = (const float4*)(x + (size_t)blockIdx.x * (16 * 256));
    float4* sd = (float4*)sx_s;
    for (int e = tid; e < 16 * 64; e += 256) sd[e] = xs[e];
    if (tid < 16) sx_s[16 * 256 + tid] = 0.f;
  }
  bf16x8 a1f = conv1_afrag(w1, ws[ST1 + b], b, q);
  f32x4 c1i;
#pragma unroll
  for (int r = 0; r < 4; ++r) c1i[r] = ws[ST1 + 16 + 4 * q + r];
  bf16x8 b2h[4];   // A-side: [ks][nt], m=ch=b, raw
#pragma unroll
  for (int ks = 0; ks < 2; ++ks)
#pragma unroll
    for (int nt = 0; nt < 2; ++nt) {
      bf16x8 vh;
#pragma unroll
      for (int j = 0; j < 8; ++j) {
        int kk = 8 * (q & 1) + j, dj = q >> 1;
        vh[j] = (short)f2bf(w2[(nt * 16 + b) * 64 + kk * 4 + ks * 2 + dj]);
      }
      b2h[ks * 2 + nt] = vh;
    }
  const float vb = (b < 13) ? 1.f : 0.f;
  const int colAr = (b + (q >> 1) < 15) ? (b + (q >> 1)) : 15;
  const int offAl = colAr * A1S + 8 * (q & 1);
  __syncthreads();

  float s2r[2][4] = {{0.f,0.f,0.f,0.f},{0.f,0.f,0.f,0.f}};
  float q2r[2][4] = {{0.f,0.f,0.f,0.f},{0.f,0.f,0.f,0.f}};
  short* ph = a1h + w * (2 * A1B);
#pragma unroll 1
  for (int t = 0; t < 4; ++t) {
    const float* sxi = sx_s + (w * 4 + t) * 256;
    conv1_mfma(sxi, ph, 0, b, q, a1f, c1i);
    __builtin_amdgcn_wave_barrier();
#pragma unroll 1
    for (int i = 0; i < 13; ++i) {
      conv1_mfma(sxi, ph, i + 1, b, q, a1f, c1i);
      __builtin_amdgcn_wave_barrier();
      bf16x8 ah0 = *(const bf16x8*)(ph + (i & 1) * A1B + offAl);
      bf16x8 ah1 = *(const bf16x8*)(ph + ((i + 1) & 1) * A1B + offAl);
      f32x4 acc2[2] = {{0.f,0.f,0.f,0.f},{0.f,0.f,0.f,0.f}};
#pragma unroll
      for (int nt = 0; nt < 2; ++nt) {
        acc2[nt] = __builtin_amdgcn_mfma_f32_16x16x32_bf16(b2h[nt], ah0, acc2[nt], 0, 0, 0);
        acc2[nt] = __builtin_amdgcn_mfma_f32_16x16x32_bf16(b2h[2 + nt], ah1, acc2[nt], 0, 0, 0);
      }
#pragma unroll
      for (int nt = 0; nt < 2; ++nt)
#pragma unroll
        for (int r = 0; r < 4; ++r) {
          float ym = acc2[nt][r] * vb;
          s2r[nt][r] += ym;
          q2r[nt][r] = fmaf(ym, acc2[nt][r], q2r[nt][r]);
        }
      __builtin_amdgcn_wave_barrier();
    }
  }
  // reduce over the 16 pix-lanes (b); lane b==0 holds ch = nt*16+4q+r
#pragma unroll
  for (int nt = 0; nt < 2; ++nt)
#pragma unroll
    for (int r = 0; r < 4; ++r) {
      float sv = s2r[nt][r], qv = q2r[nt][r];
      sv += __shfl_xor(sv, 1); sv += __shfl_xor(sv, 2);
      sv += __shfl_xor(sv, 4); sv += __shfl_xor(sv, 8);
      qv += __shfl_xor(qv, 1); qv += __shfl_xor(qv, 2);
      qv += __shfl_xor(qv, 4); qv += __shfl_xor(qv, 8);
      if (b == 0) {
        redf[w * 64 + nt * 16 + 4 * q + r]      = sv;
        redf[w * 64 + 32 + nt * 16 + 4 * q + r] = qv;
      }
    }
  __syncthreads();
  if (tid < 64)
    ws[P2P_OFF + blockIdx.x * 64 + tid] =
        redf[tid] + redf[64 + tid] + redf[128 + tid] + redf[192 + tid];
}

// BN2 finalize, one block per channel (reduces [1024][64] partials).
__global__ __launch_bounds__(256) void k_stats2(
    const float* __restrict__ gamma, const float* __restrict__ beta,
    float* __restrict__ ws)
{
  const int c = blockIdx.x, tid = threadIdx.x;
  const int w = tid >> 6, lane = tid & 63;
  __shared__ float rs[4], rq[4];
  float s = 0.f, q = 0.f;
#pragma unroll 4
  for (int i = tid; i < 1024; i += 256) {
    s += ws[P2P_OFF + i * 64 + c];
    q += ws[P2P_OFF + i * 64 + 32 + c];
  }
#pragma unroll
  for (int d = 1; d < 64; d <<= 1) {
    s += __shfl_xor(s, d);
    q += __shfl_xor(q, d);
  }
  if (lane == 0) { rs[w] = s; rq[w] = q; }
  __syncthreads();
  if (tid == 0) {
    float st = rs[0] + rs[1] + rs[2] + rs[3];
    float qt = rq[0] + rq[1] + rq[2] + rq[3];
    const float inv_n = 1.0f / (16384.0f * 169.0f);
    float mean = st * inv_n;
    float var  = qt * inv_n - mean * mean;
    float sv   = gamma[c] * rsqrtf(var + 1e-5f);
    ws[ST2 + c]      = sv;
    ws[ST2 + 32 + c] = beta[c] - mean * sv;
  }
}

// K5: conv1 + conv2 (both MFMA, BN-folded) -> a2 direct global stores + xt
// syrk for BN3 second moments -> block partials.
__global__ __launch_bounds__(256) void k5_a2(
    const float* __restrict__ x, const float* __restrict__ w1,
    const float* __restrict__ w2, float* __restrict__ ws,
    short* __restrict__ a2g, float* __restrict__ parts)
{
  __shared__ float sx_s[16 * 256 + 16];          // reused as redc at the end
  __shared__ alignas(16) short a1h[4 * 2 * A1B];
  __shared__ alignas(16) short xt4[4 * 32 * 40]; // [w][ch32][pos32+pad8]
  __shared__ float s2red[4 * 32];
  const int tid = threadIdx.x, w = tid >> 6, lane = tid & 63;
  const int b = lane & 15, q = lane >> 4;
  {
    const float4* xs = (const float4*)(x + (size_t)blockIdx.x * (16 * 256));
    float4* sd = (float4*)sx_s;
    for (int e = tid; e < 16 * 64; e += 256) sd[e] = xs[e];
    if (tid < 16) sx_s[16 * 256 + tid] = 0.f;
  }
  bf16x8 a1f = conv1_afrag(w1, ws[ST1 + b], b, q);
  f32x4 c1i;
#pragma unroll
  for (int r = 0; r < 4; ++r) c1i[r] = ws[ST1 + 16 + 4 * q + r];
  bf16x8 b2h[4];   // A-side: [ks][nt], m=ch=b, scaled by s2[nt*16+b]
#pragma unroll
  for (int ks = 0; ks < 2; ++ks)
#pragma unroll
    for (int nt = 0; nt < 2; ++nt) {
      float rs2b = ws[ST2 + nt * 16 + b];
      bf16x8 vh;
#pragma unroll
      for (int j = 0; j < 8; ++j) {
        int kk = 8 * (q & 1) + j, dj = q >> 1;
        vh[j] = (short)f2bf(w2[(nt * 16 + b) * 64 + kk * 4 + ks * 2 + dj] * rs2b);
      }
      b2h[ks * 2 + nt] = vh;
    }
  f32x4 c2i[2];
#pragma unroll
  for (int nt = 0; nt < 2; ++nt)
#pragma unroll
    for (int r = 0; r < 4; ++r)
      c2i[nt][r] = (b < 13) ? ws[ST2 + 32 + nt * 16 + 4 * q + r] : -1e30f;
  const int colAr = (b + (q >> 1) < 15) ? (b + (q >> 1)) : 15;
  const int offAl = colAr * A1S + 8 * (q & 1);
  short* xt = xt4 + w * 1280;
  __syncthreads();

  f32x4 accT0 = {0.f,0.f,0.f,0.f}, accT1 = {0.f,0.f,0.f,0.f},
        accT2 = {0.f,0.f,0.f,0.f};
  float s2aR[2][4] = {{0.f,0.f,0.f,0.f},{0.f,0.f,0.f,0.f}};
  short* ph = a1h + w * (2 * A1B);
#pragma unroll 1
  for (int t = 0; t < 4; ++t) {
    const int img = blockIdx.x * 16 + w * 4 + t;
    const float* sxi = sx_s + (w * 4 + t) * 256;
    conv1_mfma(sxi, ph, 0, b, q, a1f, c1i);
    __builtin_amdgcn_wave_barrier();
#pragma unroll 1
    for (int i = 0; i < 13; ++i) {
      conv1_mfma(sxi, ph, i + 1, b, q, a1f, c1i);
      __builtin_amdgcn_wave_barrier();
      bf16x8 ah0 = *(const bf16x8*)(ph + (i & 1) * A1B + offAl);
      bf16x8 ah1 = *(const bf16x8*)(ph + ((i + 1) & 1) * A1B + offAl);
#pragma unroll
      for (int nt = 0; nt < 2; ++nt) {
        f32x4 acc2 = c2i[nt];
        acc2 = __builtin_amdgcn_mfma_f32_16x16x32_bf16(b2h[nt], ah0, acc2, 0, 0, 0);
        acc2 = __builtin_amdgcn_mfma_f32_16x16x32_bf16(b2h[2 + nt], ah1, acc2, 0, 0, 0);
        float vm[4];
#pragma unroll
        for (int r = 0; r < 4; ++r) {
          vm[r] = acc2[r] > 0.f ? acc2[r] : 0.f;
          s2aR[nt][r] += vm[r];
          xt[(nt * 16 + 4 * q + r) * 40 + (i & 1) * 16 + b] = cvtbf(vm[r]);
        }
        if (b < 13) {
          uint2 pk;
          pk.x = pkbf(vm[0], vm[1]);
          pk.y = pkbf(vm[2], vm[3]);
          *(uint2*)(a2g + (size_t)img * 5408 + (size_t)(i * 13 + b) * 32 +
                    nt * 16 + 4 * q) = pk;
        }
      }
      __builtin_amdgcn_wave_barrier();
      if (i & 1) {   // syrk over position pair (i-1, i)
        bf16x8 xf0 = *(const bf16x8*)(xt + b * 40 + 8 * q);
        bf16x8 xf1 = *(const bf16x8*)(xt + (16 + b) * 40 + 8 * q);
        accT0 = __builtin_amdgcn_mfma_f32_16x16x32_bf16(xf0, xf0, accT0, 0, 0, 0);
        accT1 = __builtin_amdgcn_mfma_f32_16x16x32_bf16(xf0, xf1, accT1, 0, 0, 0);
        accT2 = __builtin_amdgcn_mfma_f32_16x16x32_bf16(xf1, xf1, accT2, 0, 0, 0);
      }
      __builtin_amdgcn_wave_barrier();
    }
    // leftover row 12 (parity 0): zero parity-1 halves, final syrk
    {
      uint2 z; z.x = 0u; z.y = 0u;
      *(uint2*)(xt + b * 40 + 16 + 4 * q) = z;
      *(uint2*)(xt + (16 + b) * 40 + 16 + 4 * q) = z;
      __builtin_amdgcn_wave_barrier();
      bf16x8 xf0 = *(const bf16x8*)(xt + b * 40 + 8 * q);
      bf16x8 xf1 = *(const bf16x8*)(xt + (16 + b) * 40 + 8 * q);
      accT0 = __builtin_amdgcn_mfma_f32_16x16x32_bf16(xf0, xf0, accT0, 0, 0, 0);
      accT1 = __builtin_amdgcn_mfma_f32_16x16x32_bf16(xf0, xf1, accT1, 0, 0, 0);
      accT2 = __builtin_amdgcn_mfma_f32_16x16x32_bf16(xf1, xf1, accT2, 0, 0, 0);
      __builtin_amdgcn_wave_barrier();
    }
  }
  // S2: reduce over pix-lanes b; lane b==0 holds ch = nt*16+4q+r
#pragma unroll
  for (int nt = 0; nt < 2; ++nt)
#pragma unroll
    for (int r = 0; r < 4; ++r) {
      float sv = s2aR[nt][r];
      sv += __shfl_xor(sv, 1); sv += __shfl_xor(sv, 2);
      sv += __shfl_xor(sv, 4); sv += __shfl_xor(sv, 8);
      if (b == 0) s2red[w * 32 + nt * 16 + 4 * q + r] = sv;
    }
  float* redc = sx_s;   // wave w writes only into its own sx quarter
#pragma unroll
  for (int rr = 0; rr < 4; ++rr) {
    int m = 4 * q + rr;
    redc[w * 1024 + 0   + m * 16 + b] = accT0[rr];
    redc[w * 1024 + 256 + m * 16 + b] = accT1[rr];
    redc[w * 1024 + 512 + m * 16 + b] = accT2[rr];
  }
  __syncthreads();
  for (int e = tid; e < 768; e += 256)
    parts[blockIdx.x * 800 + e] =
        redc[e] + redc[1024 + e] + redc[2048 + e] + redc[3072 + e];
  if (tid < 32)
    parts[blockIdx.x * 800 + 768 + tid] =
        s2red[tid] + s2red[32 + tid] + s2red[64 + tid] + s2red[96 + tid];
}

// K_statsC3: 800 blocks reduce parts [1024][800] -> C2R; last block runs the
// BN3 finalize (mean = w3^T S2 /N, E[y3^2] = w3^T C2 w3 /N) with 256 threads.
__global__ __launch_bounds__(256) void k_statsC3(
    const float* __restrict__ parts, const float* __restrict__ w3,
    const float* __restrict__ gamma, const float* __restrict__ beta,
    float* __restrict__ ws)
{
  __shared__ float rs[4];
  __shared__ float rc[800];
  __shared__ float eb[320];
  __shared__ bool islast;
  const int e = blockIdx.x, tid = threadIdx.x;
  const int w = tid >> 6, lane = tid & 63;
  float s = 0.f;
#pragma unroll 4
  for (int i = tid; i < 1024; i += 256) s += parts[i * 800 + e];
#pragma unroll
  for (int d = 1; d < 64; d <<= 1) s += __shfl_xor(s, d);
  if (lane == 0) rs[w] = s;
  __syncthreads();
  if (tid == 0) {
    ws[C2R_OFF + e] = rs[0] + rs[1] + rs[2] + rs[3];
    __threadfence();
    unsigned old = atomicAdd((unsigned*)ws + CNT_OFF + 1, 1u);
    islast = (old == 799u);
  }
  __syncthreads();
  if (!islast) return;
  for (int i = tid; i < 800; i += 256) rc[i] = aload(ws + C2R_OFF + i);
  __syncthreads();
  {
    const int c3 = tid & 63, seg = tid >> 6;
    float wr[32];
#pragma unroll
    for (int k = 0; k < 32; ++k) wr[k] = w3[c3 * 32 + k];
    float e2p = 0.f;
    for (int a = seg * 4; a < seg * 4 + 4; ++a)
#pragma unroll
      for (int bb = 0; bb < 16; ++bb) {
        e2p += wr[a] * wr[bb] * rc[a * 16 + bb];                  // T00
        e2p += wr[16 + a] * wr[16 + bb] * rc[512 + a * 16 + bb];  // T11
        e2p += 2.f * wr[a] * wr[16 + bb] * rc[256 + a * 16 + bb]; // T01
      }
    eb[seg * 64 + c3] = e2p;
    if (seg == 0) {
      float msum = 0.f;
#pragma unroll
      for (int k = 0; k < 32; ++k) msum += wr[k] * rc[768 + k];
      eb[256 + c3] = msum;
    }
  }
  __syncthreads();
  if (tid < 64) {
    const float inv_n = 1.0f / (16384.0f * 169.0f);
    float e2 = eb[tid] + eb[64 + tid] + eb[128 + tid] + eb[192 + tid];
    float mean = eb[256 + tid] * inv_n;
    float var  = e2 * inv_n - mean * mean;
    float sv   = gamma[tid] * rsqrtf(var + 1e-5f);
    ws[ST3 + tid]      = sv;
    ws[ST3 + 64 + tid] = beta[tid] - mean * sv;
  }
}

// K7: read packed a2 -> conv3(bn3-folded)+relu (MFMA) -> FC (MFMA).
__global__ __launch_bounds__(256) void k7_fc(
    const short* __restrict__ a2g, const float* __restrict__ w3,
    const float* __restrict__ fcb, const float* __restrict__ ws,
    float* __restrict__ out)
{
  __shared__ alignas(16) short a3buf[16 * A3P];
  const int tid = threadIdx.x, w = tid >> 6, lane = tid & 63;
  const int b = lane & 15, q = lane >> 4;
  bf16x8 b3h[4];     // B-side: n=ch=nt*16+b, scaled by s3
  f32x4 c3i[4];
#pragma unroll
  for (int nt = 0; nt < 4; ++nt) {
    float s3 = ws[ST3 + nt * 16 + b];
    float t3 = ws[ST3 + 64 + nt * 16 + b];
    bf16x8 vh;
#pragma unroll
    for (int j = 0; j < 8; ++j)
      vh[j] = (short)f2bf(w3[(nt * 16 + b) * 32 + 8 * q + j] * s3);
    b3h[nt] = vh;
    c3i[nt][0] = t3;                          // pix = 4q valid always
#pragma unroll
    for (int r = 1; r < 4; ++r)
      c3i[nt][r] = (q < 3) ? t3 : -1e30f;     // pix 4q+r invalid at q==3
  }
  const bf16x8* fcB = (const bf16x8*)ws;
  f32x4 accF = {0.f, 0.f, 0.f, 0.f};
  const int pixc = (b < 12) ? b : 12;   // clamp pad rows (relu(-1e30)=0 masks)
  size_t ib[4];
#pragma unroll
  for (int t = 0; t < 4; ++t)
    ib[t] = (size_t)(blockIdx.x * 16 + w * 4 + t) * 5408;
  bf16x8 a2pre[4];
#pragma unroll
  for (int t = 0; t < 4; ++t)
    a2pre[t] = *(const bf16x8*)(a2g + ib[t] + pixc * 32 + 8 * q);

#pragma unroll 1
  for (int i = 0; i < 13; ++i) {
    bf16x8 a2cur[4];
#pragma unroll
    for (int t = 0; t < 4; ++t) a2cur[t] = a2pre[t];
    if (i < 12) {
#pragma unroll
      for (int t = 0; t < 4; ++t)
        a2pre[t] = *(const bf16x8*)(a2g + ib[t] +
                                    (size_t)((i + 1) * 13 + pixc) * 32 + 8 * q);
    }
#pragma unroll
    for (int t = 0; t < 4; ++t) {
      const int g = w * 4 + t;
#pragma unroll
      for (int nt = 0; nt < 4; ++nt) {
        f32x4 acc3 = c3i[nt];
        acc3 = __builtin_amdgcn_mfma_f32_16x16x32_bf16(a2cur[t], b3h[nt], acc3, 0, 0, 0);
        float v0 = acc3[0] > 0.f ? acc3[0] : 0.f;
        float v1 = acc3[1] > 0.f ? acc3[1] : 0.f;
        float v2 = acc3[2] > 0.f ? acc3[2] : 0.f;
        float v3 = acc3[3] > 0.f ? acc3[3] : 0.f;
        uint2 pk2;
        pk2.x = pkbf(v0, v1);
        pk2.y = pkbf(v2, v3);
        *(uint2*)(a3buf + g * A3P + (nt * 16 + b) * 16 + 4 * q) = pk2;
      }
    }
    __syncthreads();          // a3buf complete for all 16 images
#pragma unroll
    for (int mm = 0; mm < 8; ++mm) {
      bf16x8 af = *(const bf16x8*)(a3buf + b * A3P + w * 256 + mm * 32 + 8 * q);
      bf16x8 bw = fcB[((i * 32 + w * 8 + mm) * 16 + b) * 4 + q];
      accF = __builtin_amdgcn_mfma_f32_16x16x32_bf16(af, bw, accF, 0, 0, 0);
    }
    __syncthreads();          // before next row overwrites a3buf
  }

  float* redf7 = (float*)a3buf;
#pragma unroll
  for (int r = 0; r < 4; ++r)
    redf7[w * 256 + (4 * q + r) * 16 + b] = accF[r];
  __syncthreads();
  if (tid < 160) {
    int img = tid / 10, jj = tid - img * 10;
    float s = redf7[img * 16 + jj] + redf7[256 + img * 16 + jj] +
              redf7[512 + img * 16 + jj] + redf7[768 + img * 16 + jj];
    out[(blockIdx.x * 16 + img) * 10 + jj] = s + fcb[jj];
  }
}

extern "C" void kernel_launch(void* const* d_in, const int* in_sizes, int n_in,
                              void* d_out, int out_size, void* d_ws, size_t ws_size,
                              hipStream_t stream) {
  (void)in_sizes; (void)n_in; (void)out_size; (void)ws_size;
  const float* x   = (const float*)d_in[0];
  const float* w1  = (const float*)d_in[1];
  const float* w2  = (const float*)d_in[2];
  const float* w3  = (const float*)d_in[3];
  const float* g1  = (const float*)d_in[4];
  const float* b1  = (const float*)d_in[5];
  const float* g2  = (const float*)d_in[6];
  const float* b2  = (const float*)d_in[7];
  const float* g3  = (const float*)d_in[8];
  const float* b3  = (const float*)d_in[9];
  const float* fcw = (const float*)d_in[10];
  const float* fcb = (const float*)d_in[11];
  float* out = (float*)d_out;
  float* ws  = (float*)d_ws;
  short* a2g = (short*)((char*)d_ws + A2G_BYTE);
  float* parts = ws + PARTS_OFF;

  k01<<<1440, 256, 0, stream>>>(x, fcw, parts, (unsigned int*)ws);
  k_stats1m<<<256, 256, 0, stream>>>(parts, w1, g1, b1, ws);
  k3_conv2_stats<<<1024, 256, 0, stream>>>(x, w1, w2, ws);
  k_stats2<<<32, 256, 0, stream>>>(g2, b2, ws);
  k5_a2<<<1024, 256, 0, stream>>>(x, w1, w2, ws, a2g, parts);
  k_statsC3<<<800, 256, 0, stream>>>(parts, w3, g3, b3, ws);
  k7_fc<<<1024, 256, 0, stream>>>(a2g, w3, fcb, ws, out);
}